// Round 1
// baseline (2133.270 us; speedup 1.0000x reference)
//
#include <hip/hip_runtime.h>
#include <stdint.h>

#define D_ 2048
#define H_ 16
#define HK_ 4
#define F_ 8192
#define R_ 64
#define NTOK_ 2048
#define EPS_ 1e-5f

typedef unsigned short u16;
typedef short short8 __attribute__((ext_vector_type(8)));
typedef float f32x4 __attribute__((ext_vector_type(4)));

__constant__ float NF4_TAB[16] = {
  -1.0f, -0.6961928009986877f, -0.5250730514526367f, -0.39491748809814453f,
  -0.28444138169288635f, -0.18477343022823334f, -0.09105003625154495f, 0.0f,
  0.07958029955625534f, 0.16093020141124725f, 0.24611230194568634f, 0.33791524171829224f,
  0.44070982933044434f, 0.5626170039176941f, 0.7229568362236023f, 1.0f };

static __device__ __forceinline__ float b2f(u16 u){ return __uint_as_float(((unsigned)u)<<16); }
static __device__ __forceinline__ u16 f2b(float f){
  unsigned u = __float_as_uint(f);
  return (u16)((u + 0x7fffu + ((u>>16)&1u)) >> 16);
}

static __device__ __forceinline__ void gl_lds16(const u16* g, u16* l){
  __builtin_amdgcn_global_load_lds((const __attribute__((address_space(1))) unsigned int*)g,
                                   (__attribute__((address_space(3))) unsigned int*)l, 16, 0, 0);
}

// ---------------- embedding gather: h[tok][:] = embed[ids[tok]][:]
__global__ void k_embed(const int* __restrict__ ids, const float* __restrict__ embed,
                        float* __restrict__ h){
  int tok = blockIdx.x;
  int id  = ids[tok];
  const float4* src = (const float4*)(embed + (size_t)id * D_);
  float4* dst = (float4*)(h + (size_t)tok * D_);
  for (int i = threadIdx.x; i < D_/4; i += 256) dst[i] = src[i];
}

// ---------------- RMSNorm: xb = bf16( h * rsqrt(mean(h^2)+eps) * w )
__global__ void k_rms(const float* __restrict__ h, const float* __restrict__ w,
                      u16* __restrict__ xb){
  __shared__ float red[4];
  int row = blockIdx.x, t = threadIdx.x;
  const float* hr = h + (size_t)row * D_;
  float ss = 0.f;
  for (int i = t; i < D_; i += 256){ float v = hr[i]; ss += v*v; }
  #pragma unroll
  for (int m = 32; m; m >>= 1) ss += __shfl_xor(ss, m, 64);
  if ((t & 63) == 0) red[t >> 6] = ss;
  __syncthreads();
  float sc = rsqrtf((red[0]+red[1]+red[2]+red[3]) * (1.0f/D_) + EPS_);
  for (int i = t; i < D_; i += 256) xb[(size_t)row*D_ + i] = f2b(hr[i]*sc*w[i]);
}

// ---------------- fold-dequant: W[n,k] = NF4[codes]*absmax + 2 * sum_r B[n,r]*A[r,k]
// tile: 128 n x 128 k, 256 threads (tn=t>>4 -> 8n, tk=t&15 -> 8k each)
__global__ __launch_bounds__(256) void k_fold(const int* __restrict__ codes,
      const float* __restrict__ absmax, const float* __restrict__ Amat,
      const float* __restrict__ Bmat, u16* __restrict__ W, int O, int I){
  __shared__ u16  A_l[64*128];     // [r][kk] bf16
  __shared__ float Bt_l[64*132];   // [r][nl], stride 132 (pad, 16B-aligned)
  __shared__ float nf4s[16];
  int t = threadIdx.x;
  int n0 = blockIdx.y*128, k0 = blockIdx.x*128;
  if (t < 16) nf4s[t] = NF4_TAB[t];
  // stage A (64 x 128) as bf16
  #pragma unroll
  for (int it = 0; it < 8; ++it){
    int fi = it*256 + t;             // float4 index, 2048 total
    int r = fi >> 5, c4 = fi & 31;
    float4 v = *(const float4*)(Amat + (size_t)r*I + k0 + c4*4);
    uint2 p; p.x = (unsigned)f2b(v.x) | ((unsigned)f2b(v.y)<<16);
    p.y = (unsigned)f2b(v.z) | ((unsigned)f2b(v.w)<<16);
    *(uint2*)&A_l[r*128 + c4*4] = p;
  }
  // stage B transposed (Bt[r][nl] = B[n0+nl][r])
  #pragma unroll
  for (int it = 0; it < 8; ++it){
    int fi = it*256 + t; int nl = fi >> 4, r4 = fi & 15;
    float4 v = *(const float4*)(Bmat + (size_t)(n0+nl)*R_ + r4*4);
    Bt_l[(r4*4+0)*132 + nl] = v.x; Bt_l[(r4*4+1)*132 + nl] = v.y;
    Bt_l[(r4*4+2)*132 + nl] = v.z; Bt_l[(r4*4+3)*132 + nl] = v.w;
  }
  __syncthreads();
  int tk = t & 15, tn = t >> 4;
  float acc[8][8];
  #pragma unroll
  for (int j = 0; j < 8; ++j)
    #pragma unroll
    for (int q = 0; q < 8; ++q) acc[j][q] = 0.f;
  for (int r = 0; r < 64; ++r){
    short8 a8 = *(const short8*)&A_l[r*128 + tk*8];
    float av[8];
    #pragma unroll
    for (int q = 0; q < 8; ++q) av[q] = b2f((u16)a8[q]);
    float4 b0 = *(const float4*)&Bt_l[r*132 + tn*8];
    float4 b1 = *(const float4*)&Bt_l[r*132 + tn*8 + 4];
    float bv[8] = {b0.x,b0.y,b0.z,b0.w,b1.x,b1.y,b1.z,b1.w};
    #pragma unroll
    for (int j = 0; j < 8; ++j)
      #pragma unroll
      for (int q = 0; q < 8; ++q) acc[j][q] += bv[j]*av[q];
  }
  int kb = k0 + tk*8;
  #pragma unroll
  for (int j = 0; j < 8; ++j){
    int n = n0 + tn*8 + j;
    float am = absmax[(size_t)n*(I>>6) + (kb>>6)];
    int4 c0 = *(const int4*)(codes + (size_t)n*I + kb);
    int4 c1 = *(const int4*)(codes + (size_t)n*I + kb + 4);
    u16 o[8];
    o[0]=f2b(nf4s[c0.x&15]*am + 2.0f*acc[j][0]);
    o[1]=f2b(nf4s[c0.y&15]*am + 2.0f*acc[j][1]);
    o[2]=f2b(nf4s[c0.z&15]*am + 2.0f*acc[j][2]);
    o[3]=f2b(nf4s[c0.w&15]*am + 2.0f*acc[j][3]);
    o[4]=f2b(nf4s[c1.x&15]*am + 2.0f*acc[j][4]);
    o[5]=f2b(nf4s[c1.y&15]*am + 2.0f*acc[j][5]);
    o[6]=f2b(nf4s[c1.z&15]*am + 2.0f*acc[j][6]);
    o[7]=f2b(nf4s[c1.w&15]*am + 2.0f*acc[j][7]);
    uint4 pk;
    pk.x=(unsigned)o[0]|((unsigned)o[1]<<16); pk.y=(unsigned)o[2]|((unsigned)o[3]<<16);
    pk.z=(unsigned)o[4]|((unsigned)o[5]<<16); pk.w=(unsigned)o[6]|((unsigned)o[7]<<16);
    *(uint4*)(W + (size_t)n*I + kb) = pk;
  }
}

// ---------------- main GEMM: C[m,n] = sum_k A[m,k]*B[n,k]  (both bf16 row-major, ld=K)
// EPI 0: Cb[m,n]=bf16(acc)   EPI 1: Cf[m,n]+=acc (f32 residual)
template<int EPI>
__global__ __launch_bounds__(256) void k_gemm(const u16* __restrict__ A,
      const u16* __restrict__ B, float* __restrict__ Cf, u16* __restrict__ Cb,
      int M, int N, int K){
  __shared__ u16 As[128*32];
  __shared__ u16 Bs[128*32];
  int t = threadIdx.x;
  int n0 = blockIdx.x*128, m0 = blockIdx.y*128;
  int w = t >> 6, lane = t & 63;
  int mw = (w >> 1)*64, nw = (w & 1)*64;
  int lr = lane & 15, lg = lane >> 4;
  f32x4 acc[4][4];
  #pragma unroll
  for (int mt = 0; mt < 4; ++mt)
    #pragma unroll
    for (int nt = 0; nt < 4; ++nt) acc[mt][nt] = (f32x4){0.f,0.f,0.f,0.f};
  const u16* Ag = A + (size_t)(m0 + (t>>2))*K + (t&3)*8;
  const u16* Bg = B + (size_t)(n0 + (t>>2))*K + (t&3)*8;
  u16* AsD = As + t*8;
  u16* BsD = Bs + t*8;
  for (int kb = 0; kb < K; kb += 32){
    __syncthreads();
    gl_lds16(Ag + kb,               AsD);
    gl_lds16(Ag + (size_t)64*K + kb, AsD + 2048);
    gl_lds16(Bg + kb,               BsD);
    gl_lds16(Bg + (size_t)64*K + kb, BsD + 2048);
    __builtin_amdgcn_s_waitcnt(0x0f70);   // vmcnt(0)
    __syncthreads();
    short8 af[4], bf_[4];
    #pragma unroll
    for (int mt = 0; mt < 4; ++mt) af[mt] = *(const short8*)&As[(mw + mt*16 + lr)*32 + lg*8];
    #pragma unroll
    for (int nt = 0; nt < 4; ++nt) bf_[nt] = *(const short8*)&Bs[(nw + nt*16 + lr)*32 + lg*8];
    #pragma unroll
    for (int mt = 0; mt < 4; ++mt)
      #pragma unroll
      for (int nt = 0; nt < 4; ++nt)
        acc[mt][nt] = __builtin_amdgcn_mfma_f32_16x16x32_bf16(af[mt], bf_[nt], acc[mt][nt], 0, 0, 0);
  }
  #pragma unroll
  for (int mt = 0; mt < 4; ++mt)
    #pragma unroll
    for (int nt = 0; nt < 4; ++nt){
      int col = n0 + nw + nt*16 + lr;
      #pragma unroll
      for (int rg = 0; rg < 4; ++rg){
        int row = m0 + mw + mt*16 + lg*4 + rg;
        float v = acc[mt][nt][rg];
        size_t idx = (size_t)row*N + col;
        if (EPI == 0) Cb[idx] = f2b(v);
        else          Cf[idx] += v;
      }
    }
}

// ---------------- RoPE in-place on bf16 [tok][nh*128]
__global__ void k_rope(u16* __restrict__ x, int nh){
  int i = blockIdx.x*256 + threadIdx.x;
  int d = i & 63; int rem = i >> 6; int hh = rem % nh; int tok = rem / nh;
  int s = tok & 127;
  size_t base = (size_t)tok*nh*128 + hh*128 + d;
  float x1 = b2f(x[base]), x2 = b2f(x[base+64]);
  float inv = exp2f(-(float)d * 0.20762050581352868f);  // (1/64)*log2(10000)
  float ang = (float)s * inv;
  float sn = sinf(ang), cs = cosf(ang);
  x[base]      = f2b(x1*cs - x2*sn);
  x[base+64]   = f2b(x2*cs + x1*sn);
}

// ---------------- attention: one block per (b, head); S=128, HD=128
__global__ __launch_bounds__(256) void k_attn(const u16* __restrict__ q,
      const u16* __restrict__ kk, const u16* __restrict__ vv,
      const int* __restrict__ mask, u16* __restrict__ ctx){
  __shared__ u16 QP[128*128];   // Q, then P
  __shared__ u16 KV[128*128];   // K, then V^T
  int b = blockIdx.y, h = blockIdx.x;
  int t = threadIdx.x, w = t >> 6, lane = t & 63;
  int lr = lane & 15, lg = lane >> 4;
  // stage Q and K
  #pragma unroll
  for (int it = 0; it < 8; ++it){
    int fi = it*256 + t; int s = fi >> 4, c8 = fi & 15;
    *(uint4*)&QP[s*128 + c8*8] = *(const uint4*)(q  + (size_t)(b*128+s)*2048 + h*128 + c8*8);
    *(uint4*)&KV[s*128 + c8*8] = *(const uint4*)(kk + (size_t)(b*128+s)*512 + (h>>2)*128 + c8*8);
  }
  __syncthreads();
  // S = Q K^T  (wave w: rows w*32 .. w*32+31)
  f32x4 sac[2][8];
  #pragma unroll
  for (int mt = 0; mt < 2; ++mt)
    #pragma unroll
    for (int nt = 0; nt < 8; ++nt) sac[mt][nt] = (f32x4){0.f,0.f,0.f,0.f};
  for (int ks = 0; ks < 128; ks += 32){
    short8 a[2], bb[8];
    #pragma unroll
    for (int mt = 0; mt < 2; ++mt) a[mt] = *(const short8*)&QP[(w*32 + mt*16 + lr)*128 + ks + lg*8];
    #pragma unroll
    for (int nt = 0; nt < 8; ++nt) bb[nt] = *(const short8*)&KV[(nt*16 + lr)*128 + ks + lg*8];
    #pragma unroll
    for (int mt = 0; mt < 2; ++mt)
      #pragma unroll
      for (int nt = 0; nt < 8; ++nt)
        sac[mt][nt] = __builtin_amdgcn_mfma_f32_16x16x32_bf16(a[mt], bb[nt], sac[mt][nt], 0, 0, 0);
  }
  const float NEG = -1e9f, scl = 0.08838834764831845f;
  float mbias[8];
  #pragma unroll
  for (int nt = 0; nt < 8; ++nt) mbias[nt] = (mask[b*128 + nt*16 + lr] > 0) ? 0.f : NEG;
  #pragma unroll
  for (int mt = 0; mt < 2; ++mt)
    #pragma unroll
    for (int rg = 0; rg < 4; ++rg){
      int row = w*32 + mt*16 + lg*4 + rg;
      float vvv[8]; float mx = -3e38f;
      #pragma unroll
      for (int nt = 0; nt < 8; ++nt){
        int col = nt*16 + lr;
        float s_ = sac[mt][nt][rg]*scl + ((col <= row) ? mbias[nt] : NEG);
        vvv[nt] = s_; mx = fmaxf(mx, s_);
      }
      #pragma unroll
      for (int m_ = 1; m_ < 16; m_ <<= 1) mx = fmaxf(mx, __shfl_xor(mx, m_, 64));
      float sum = 0.f;
      #pragma unroll
      for (int nt = 0; nt < 8; ++nt){ vvv[nt] = __expf(vvv[nt]-mx); sum += vvv[nt]; }
      #pragma unroll
      for (int m_ = 1; m_ < 16; m_ <<= 1) sum += __shfl_xor(sum, m_, 64);
      float inv = 1.0f/sum;
      #pragma unroll
      for (int nt = 0; nt < 8; ++nt) QP[row*128 + nt*16 + lr] = f2b(vvv[nt]*inv);
    }
  __syncthreads();
  // stage V transposed: KV[d][s]
  #pragma unroll
  for (int it = 0; it < 8; ++it){
    int fi = it*256 + t; int s = fi >> 4, c8 = fi & 15;
    u16 tmp[8];
    *(uint4*)tmp = *(const uint4*)(vv + (size_t)(b*128+s)*512 + (h>>2)*128 + c8*8);
    #pragma unroll
    for (int j = 0; j < 8; ++j) KV[(c8*8+j)*128 + s] = tmp[j];
  }
  __syncthreads();
  // O = P V
  f32x4 oac[2][8];
  #pragma unroll
  for (int mt = 0; mt < 2; ++mt)
    #pragma unroll
    for (int nt = 0; nt < 8; ++nt) oac[mt][nt] = (f32x4){0.f,0.f,0.f,0.f};
  for (int ks = 0; ks < 128; ks += 32){
    short8 a[2], bb[8];
    #pragma unroll
    for (int mt = 0; mt < 2; ++mt) a[mt] = *(const short8*)&QP[(w*32 + mt*16 + lr)*128 + ks + lg*8];
    #pragma unroll
    for (int nt = 0; nt < 8; ++nt) bb[nt] = *(const short8*)&KV[(nt*16 + lr)*128 + ks + lg*8];
    #pragma unroll
    for (int mt = 0; mt < 2; ++mt)
      #pragma unroll
      for (int nt = 0; nt < 8; ++nt)
        oac[mt][nt] = __builtin_amdgcn_mfma_f32_16x16x32_bf16(a[mt], bb[nt], oac[mt][nt], 0, 0, 0);
  }
  #pragma unroll
  for (int mt = 0; mt < 2; ++mt)
    #pragma unroll
    for (int nt = 0; nt < 8; ++nt)
      #pragma unroll
      for (int rg = 0; rg < 4; ++rg){
        int row = w*32 + mt*16 + lg*4 + rg;
        int col = nt*16 + lr;
        ctx[(size_t)(b*128+row)*2048 + h*128 + col] = f2b(oac[mt][nt][rg]);
      }
}

// ---------------- silu(g)*u -> g  (bf16, vector8)
__global__ void k_silu(u16* __restrict__ g, const u16* __restrict__ u, int n8){
  int i = blockIdx.x*256 + threadIdx.x;
  if (i >= n8) return;
  u16 gv[8], uv[8];
  *(uint4*)gv = *(const uint4*)(g + (size_t)i*8);
  *(uint4*)uv = *(const uint4*)(u + (size_t)i*8);
  #pragma unroll
  for (int j = 0; j < 8; ++j){
    float x = b2f(gv[j]), y = b2f(uv[j]);
    float s = x / (1.0f + __expf(-x));
    gv[j] = f2b(s*y);
  }
  *(uint4*)(g + (size_t)i*8) = *(uint4*)gv;
}

// ---------------- final norm + last-token gather -> out[b][:]
__global__ void k_final(const float* __restrict__ h, const int* __restrict__ mask,
                        const float* __restrict__ w, float* __restrict__ out){
  __shared__ float red[4]; __shared__ int rowsh;
  int b = blockIdx.x, t = threadIdx.x;
  if (t == 0){
    int c = 0;
    for (int i = 0; i < 128; ++i) c += (mask[b*128+i] > 0);
    rowsh = b*128 + c - 1;
  }
  __syncthreads();
  const float* hr = h + (size_t)rowsh*D_;
  float ss = 0.f;
  for (int i = t; i < D_; i += 256){ float x = hr[i]; ss += x*x; }
  #pragma unroll
  for (int m = 32; m; m >>= 1) ss += __shfl_xor(ss, m, 64);
  if ((t & 63) == 0) red[t >> 6] = ss;
  __syncthreads();
  float sc = rsqrtf((red[0]+red[1]+red[2]+red[3]) * (1.0f/D_) + EPS_);
  for (int i = t; i < D_; i += 256) out[(size_t)b*D_ + i] = hr[i]*sc*w[i];
}

extern "C" void kernel_launch(void* const* d_in, const int* in_sizes, int n_in,
                              void* d_out, int out_size, void* d_ws, size_t ws_size,
                              hipStream_t stream) {
  const int*   ids       = (const int*)  d_in[0];
  const int*   mask      = (const int*)  d_in[1];
  const float* embed     = (const float*)d_in[2];
  const float* attn_norm = (const float*)d_in[3];
  const float* mlp_norm  = (const float*)d_in[4];
  const float* fin_norm  = (const float*)d_in[5];
  struct QW { const int* c; const float* am; const float* A; const float* B; };
  auto qw = [&](int i){ return QW{(const int*)d_in[i], (const float*)d_in[i+1],
                                  (const float*)d_in[i+2], (const float*)d_in[i+3]}; };
  QW Wq = qw(6), Wk = qw(10), Wv = qw(14), Wo = qw(18), Wg = qw(22), Wu = qw(26), Wd = qw(30);

  // workspace layout (needs 138,412,032 bytes)
  char* ws = (char*)d_ws;
  float* h  = (float*)(ws);                       // 2048*2048*4 = 16777216
  u16* xb   = (u16*)(ws + 16777216);              // 2048*2048*2 (x / ctx)
  u16* qb   = (u16*)(ws + 25165824);              // 2048*2048*2
  u16* kb_  = (u16*)(ws + 33554432);              // 2048*512*2
  u16* vb   = (u16*)(ws + 35651584);              // 2048*512*2
  u16* gb   = (u16*)(ws + 37748736);              // 2048*8192*2
  u16* ub   = (u16*)(ws + 71303168);              // 2048*8192*2
  u16* Wb   = (u16*)(ws + 104857600);             // up to 8192*2048*2

  k_embed<<<NTOK_, 256, 0, stream>>>(ids, embed, h);

  for (int l = 0; l < 2; ++l){
    // ---- attention block
    k_rms<<<NTOK_, 256, 0, stream>>>(h, attn_norm + l*D_, xb);
    k_fold<<<dim3(16,16), 256, 0, stream>>>(Wq.c + (size_t)l*D_*D_, Wq.am + (size_t)l*D_*32,
        Wq.A + (size_t)l*R_*D_, Wq.B + (size_t)l*D_*R_, Wb, D_, D_);
    k_gemm<0><<<dim3(16,16), 256, 0, stream>>>(xb, Wb, nullptr, qb, NTOK_, D_, D_);
    k_fold<<<dim3(16,4), 256, 0, stream>>>(Wk.c + (size_t)l*512*D_, Wk.am + (size_t)l*512*32,
        Wk.A + (size_t)l*R_*D_, Wk.B + (size_t)l*512*R_, Wb, 512, D_);
    k_gemm<0><<<dim3(4,16), 256, 0, stream>>>(xb, Wb, nullptr, kb_, NTOK_, 512, D_);
    k_fold<<<dim3(16,4), 256, 0, stream>>>(Wv.c + (size_t)l*512*D_, Wv.am + (size_t)l*512*32,
        Wv.A + (size_t)l*R_*D_, Wv.B + (size_t)l*512*R_, Wb, 512, D_);
    k_gemm<0><<<dim3(4,16), 256, 0, stream>>>(xb, Wb, nullptr, vb, NTOK_, 512, D_);
    k_rope<<<8192, 256, 0, stream>>>(qb, H_);
    k_rope<<<2048, 256, 0, stream>>>(kb_, HK_);
    k_attn<<<dim3(16,16), 256, 0, stream>>>(qb, kb_, vb, mask, xb);  // ctx -> xb
    k_fold<<<dim3(16,16), 256, 0, stream>>>(Wo.c + (size_t)l*D_*D_, Wo.am + (size_t)l*D_*32,
        Wo.A + (size_t)l*R_*D_, Wo.B + (size_t)l*D_*R_, Wb, D_, D_);
    k_gemm<1><<<dim3(16,16), 256, 0, stream>>>(xb, Wb, h, nullptr, NTOK_, D_, D_);
    // ---- MLP block
    k_rms<<<NTOK_, 256, 0, stream>>>(h, mlp_norm + l*D_, xb);
    k_fold<<<dim3(16,64), 256, 0, stream>>>(Wg.c + (size_t)l*F_*D_, Wg.am + (size_t)l*F_*32,
        Wg.A + (size_t)l*R_*D_, Wg.B + (size_t)l*F_*R_, Wb, F_, D_);
    k_gemm<0><<<dim3(64,16), 256, 0, stream>>>(xb, Wb, nullptr, gb, NTOK_, F_, D_);
    k_fold<<<dim3(16,64), 256, 0, stream>>>(Wu.c + (size_t)l*F_*D_, Wu.am + (size_t)l*F_*32,
        Wu.A + (size_t)l*R_*D_, Wu.B + (size_t)l*F_*R_, Wb, F_, D_);
    k_gemm<0><<<dim3(64,16), 256, 0, stream>>>(xb, Wb, nullptr, ub, NTOK_, F_, D_);
    k_silu<<<8192, 256, 0, stream>>>(gb, ub, NTOK_*F_/8);
    k_fold<<<dim3(64,16), 256, 0, stream>>>(Wd.c + (size_t)l*D_*F_, Wd.am + (size_t)l*D_*128,
        Wd.A + (size_t)l*R_*F_, Wd.B + (size_t)l*D_*R_, Wb, D_, F_);
    k_gemm<1><<<dim3(16,16), 256, 0, stream>>>(gb, Wb, h, nullptr, NTOK_, D_, F_);
  }
  k_final<<<16, 256, 0, stream>>>(h, mask, fin_norm, (float*)d_out);
}

// Round 2
// 2020.888 us; speedup vs baseline: 1.0556x; 1.0556x over previous
//
#include <hip/hip_runtime.h>
#include <stdint.h>

#define D_ 2048
#define H_ 16
#define HK_ 4
#define F_ 8192
#define R_ 64
#define NTOK_ 2048
#define EPS_ 1e-5f

typedef unsigned short u16;
typedef short short8 __attribute__((ext_vector_type(8)));
typedef float f32x4 __attribute__((ext_vector_type(4)));

__constant__ float NF4_TAB[16] = {
  -1.0f, -0.6961928009986877f, -0.5250730514526367f, -0.39491748809814453f,
  -0.28444138169288635f, -0.18477343022823334f, -0.09105003625154495f, 0.0f,
  0.07958029955625534f, 0.16093020141124725f, 0.24611230194568634f, 0.33791524171829224f,
  0.44070982933044434f, 0.5626170039176941f, 0.7229568362236023f, 1.0f };

static __device__ __forceinline__ float b2f(u16 u){ return __uint_as_float(((unsigned)u)<<16); }
static __device__ __forceinline__ u16 f2b(float f){
  unsigned u = __float_as_uint(f);
  return (u16)((u + 0x7fffu + ((u>>16)&1u)) >> 16);
}

static __device__ __forceinline__ void gl_lds16(const u16* g, u16* l){
  __builtin_amdgcn_global_load_lds((const __attribute__((address_space(1))) unsigned int*)g,
                                   (__attribute__((address_space(3))) unsigned int*)l, 16, 0, 0);
}

// ---------------- embedding gather
__global__ void k_embed(const int* __restrict__ ids, const float* __restrict__ embed,
                        float* __restrict__ h){
  int tok = blockIdx.x;
  int id  = ids[tok];
  const float4* src = (const float4*)(embed + (size_t)id * D_);
  float4* dst = (float4*)(h + (size_t)tok * D_);
  for (int i = threadIdx.x; i < D_/4; i += 256) dst[i] = src[i];
}

// ---------------- RMSNorm
__global__ void k_rms(const float* __restrict__ h, const float* __restrict__ w,
                      u16* __restrict__ xb){
  __shared__ float red[4];
  int row = blockIdx.x, t = threadIdx.x;
  const float* hr = h + (size_t)row * D_;
  float ss = 0.f;
  for (int i = t; i < D_; i += 256){ float v = hr[i]; ss += v*v; }
  #pragma unroll
  for (int m = 32; m; m >>= 1) ss += __shfl_xor(ss, m, 64);
  if ((t & 63) == 0) red[t >> 6] = ss;
  __syncthreads();
  float sc = rsqrtf((red[0]+red[1]+red[2]+red[3]) * (1.0f/D_) + EPS_);
  for (int i = t; i < D_; i += 256) xb[(size_t)row*D_ + i] = f2b(hr[i]*sc*w[i]);
}

// ---------------- fold-dequant: W[n,k] = NF4[codes]*absmax + 2 * B@A
__global__ __launch_bounds__(256) void k_fold(const int* __restrict__ codes,
      const float* __restrict__ absmax, const float* __restrict__ Amat,
      const float* __restrict__ Bmat, u16* __restrict__ W, int O, int I){
  __shared__ u16  A_l[64*128];
  __shared__ float Bt_l[64*132];
  __shared__ float nf4s[16];
  int t = threadIdx.x;
  int n0 = blockIdx.y*128, k0 = blockIdx.x*128;
  if (t < 16) nf4s[t] = NF4_TAB[t];
  #pragma unroll
  for (int it = 0; it < 8; ++it){
    int fi = it*256 + t;
    int r = fi >> 5, c4 = fi & 31;
    float4 v = *(const float4*)(Amat + (size_t)r*I + k0 + c4*4);
    uint2 p; p.x = (unsigned)f2b(v.x) | ((unsigned)f2b(v.y)<<16);
    p.y = (unsigned)f2b(v.z) | ((unsigned)f2b(v.w)<<16);
    *(uint2*)&A_l[r*128 + c4*4] = p;
  }
  #pragma unroll
  for (int it = 0; it < 8; ++it){
    int fi = it*256 + t; int nl = fi >> 4, r4 = fi & 15;
    float4 v = *(const float4*)(Bmat + (size_t)(n0+nl)*R_ + r4*4);
    Bt_l[(r4*4+0)*132 + nl] = v.x; Bt_l[(r4*4+1)*132 + nl] = v.y;
    Bt_l[(r4*4+2)*132 + nl] = v.z; Bt_l[(r4*4+3)*132 + nl] = v.w;
  }
  __syncthreads();
  int tk = t & 15, tn = t >> 4;
  float acc[8][8];
  #pragma unroll
  for (int j = 0; j < 8; ++j)
    #pragma unroll
    for (int q = 0; q < 8; ++q) acc[j][q] = 0.f;
  for (int r = 0; r < 64; ++r){
    short8 a8 = *(const short8*)&A_l[r*128 + tk*8];
    float av[8];
    #pragma unroll
    for (int q = 0; q < 8; ++q) av[q] = b2f((u16)a8[q]);
    float4 b0 = *(const float4*)&Bt_l[r*132 + tn*8];
    float4 b1 = *(const float4*)&Bt_l[r*132 + tn*8 + 4];
    float bv[8] = {b0.x,b0.y,b0.z,b0.w,b1.x,b1.y,b1.z,b1.w};
    #pragma unroll
    for (int j = 0; j < 8; ++j)
      #pragma unroll
      for (int q = 0; q < 8; ++q) acc[j][q] += bv[j]*av[q];
  }
  int kb = k0 + tk*8;
  #pragma unroll
  for (int j = 0; j < 8; ++j){
    int n = n0 + tn*8 + j;
    float am = absmax[(size_t)n*(I>>6) + (kb>>6)];
    int4 c0 = *(const int4*)(codes + (size_t)n*I + kb);
    int4 c1 = *(const int4*)(codes + (size_t)n*I + kb + 4);
    u16 o[8];
    o[0]=f2b(nf4s[c0.x&15]*am + 2.0f*acc[j][0]);
    o[1]=f2b(nf4s[c0.y&15]*am + 2.0f*acc[j][1]);
    o[2]=f2b(nf4s[c0.z&15]*am + 2.0f*acc[j][2]);
    o[3]=f2b(nf4s[c0.w&15]*am + 2.0f*acc[j][3]);
    o[4]=f2b(nf4s[c1.x&15]*am + 2.0f*acc[j][4]);
    o[5]=f2b(nf4s[c1.y&15]*am + 2.0f*acc[j][5]);
    o[6]=f2b(nf4s[c1.z&15]*am + 2.0f*acc[j][6]);
    o[7]=f2b(nf4s[c1.w&15]*am + 2.0f*acc[j][7]);
    uint4 pk;
    pk.x=(unsigned)o[0]|((unsigned)o[1]<<16); pk.y=(unsigned)o[2]|((unsigned)o[3]<<16);
    pk.z=(unsigned)o[4]|((unsigned)o[5]<<16); pk.w=(unsigned)o[6]|((unsigned)o[7]<<16);
    *(uint4*)(W + (size_t)n*I + kb) = pk;
  }
}

// ---------------- main GEMM, 3-deep pipelined (raw s_barrier + vmcnt(8))
// C[m,n] = sum_k A[m,k]*B[n,k], both bf16 row-major ld=K.
// EPI 0: C0[m,n]=bf16  EPI 1: Cf[m,n]+=acc  EPI 2: split-N qkv epilogue
template<int EPI>
__global__ __launch_bounds__(256) void k_gemm(const u16* __restrict__ A,
      const u16* __restrict__ B, float* __restrict__ Cf, u16* __restrict__ C0,
      u16* __restrict__ C1, u16* __restrict__ C2, int M, int N, int K){
  __shared__ u16 SA[3][128*32];
  __shared__ u16 SB[3][128*32];
  int t = threadIdx.x;
  int n0 = blockIdx.x*128, m0 = blockIdx.y*128;
  int w = t >> 6, lane = t & 63;
  int mw = (w >> 1)*64, nw = (w & 1)*64;
  int lr = lane & 15, lg = lane >> 4;
  f32x4 acc[4][4];
  #pragma unroll
  for (int mt = 0; mt < 4; ++mt)
    #pragma unroll
    for (int nt = 0; nt < 4; ++nt) acc[mt][nt] = (f32x4){0.f,0.f,0.f,0.f};
  const u16* Ag = A + (size_t)(m0 + (t>>2))*K + (t&3)*8;
  const u16* Bg = B + (size_t)(n0 + (t>>2))*K + (t&3)*8;
  int soff = t*8;
  int niter = K >> 5;
  // issue loads for iteration `it` into buffer `buf`
  auto issue = [&](int it, int buf){
    int kb = it*32;
    gl_lds16(Ag + kb,                &SA[buf][soff]);
    gl_lds16(Ag + (size_t)64*K + kb, &SA[buf][soff + 2048]);
    gl_lds16(Bg + kb,                &SB[buf][soff]);
    gl_lds16(Bg + (size_t)64*K + kb, &SB[buf][soff + 2048]);
  };
  issue(0, 0);
  issue(1 < niter ? 1 : niter-1, 1);
  int cb = 0;
  for (int k = 0; k < niter; ++k){
    int nxt = k + 2;
    int nb = cb + 2; if (nb >= 3) nb -= 3;
    issue(nxt < niter ? nxt : niter-1, nb);   // tail: dead-buffer reissue keeps vmcnt exact
    __builtin_amdgcn_s_waitcnt(0x0F78);       // vmcnt(8): oldest 4 (iter k) complete
    __builtin_amdgcn_s_barrier();
    short8 af[4], bf_[4];
    #pragma unroll
    for (int mt = 0; mt < 4; ++mt) af[mt]  = *(const short8*)&SA[cb][(mw + mt*16 + lr)*32 + lg*8];
    #pragma unroll
    for (int nt = 0; nt < 4; ++nt) bf_[nt] = *(const short8*)&SB[cb][(nw + nt*16 + lr)*32 + lg*8];
    #pragma unroll
    for (int mt = 0; mt < 4; ++mt)
      #pragma unroll
      for (int nt = 0; nt < 4; ++nt)
        acc[mt][nt] = __builtin_amdgcn_mfma_f32_16x16x32_bf16(af[mt], bf_[nt], acc[mt][nt], 0, 0, 0);
    __builtin_amdgcn_s_barrier();
    cb = cb + 1; if (cb >= 3) cb -= 3;
  }
  __builtin_amdgcn_s_waitcnt(0x0F70);         // drain DMA before kernel end
  // epilogue
  u16* cb_ = C0; int ldc = N; int coff = n0;
  if (EPI == 2){
    if (n0 < 2048)      { cb_ = C0; ldc = 2048; coff = n0; }
    else if (n0 < 2560) { cb_ = C1; ldc = 512;  coff = n0 - 2048; }
    else                { cb_ = C2; ldc = 512;  coff = n0 - 2560; }
  }
  #pragma unroll
  for (int mt = 0; mt < 4; ++mt)
    #pragma unroll
    for (int nt = 0; nt < 4; ++nt){
      int cl = nw + nt*16 + lr;
      #pragma unroll
      for (int rg = 0; rg < 4; ++rg){
        int row = m0 + mw + mt*16 + lg*4 + rg;
        float v = acc[mt][nt][rg];
        if (EPI == 1) Cf[(size_t)row*N + n0 + cl] += v;
        else          cb_[(size_t)row*ldc + coff + cl] = f2b(v);
      }
    }
}

// ---------------- RoPE in-place on bf16 [tok][nh*128]
__global__ void k_rope(u16* __restrict__ x, int nh){
  int i = blockIdx.x*256 + threadIdx.x;
  int d = i & 63; int rem = i >> 6; int hh = rem % nh; int tok = rem / nh;
  int s = tok & 127;
  size_t base = (size_t)tok*nh*128 + hh*128 + d;
  float x1 = b2f(x[base]), x2 = b2f(x[base+64]);
  float inv = exp2f(-(float)d * 0.20762050581352868f);
  float ang = (float)s * inv;
  float sn = sinf(ang), cs = cosf(ang);
  x[base]      = f2b(x1*cs - x2*sn);
  x[base+64]   = f2b(x2*cs + x1*sn);
}

// ---------------- attention: one block per (b, head); S=128, HD=128
__global__ __launch_bounds__(256) void k_attn(const u16* __restrict__ q,
      const u16* __restrict__ kk, const u16* __restrict__ vv,
      const int* __restrict__ mask, u16* __restrict__ ctx){
  __shared__ u16 QP[128*128];
  __shared__ u16 KV[128*128];
  int b = blockIdx.y, h = blockIdx.x;
  int t = threadIdx.x, w = t >> 6, lane = t & 63;
  int lr = lane & 15, lg = lane >> 4;
  #pragma unroll
  for (int it = 0; it < 8; ++it){
    int fi = it*256 + t; int s = fi >> 4, c8 = fi & 15;
    *(uint4*)&QP[s*128 + c8*8] = *(const uint4*)(q  + (size_t)(b*128+s)*2048 + h*128 + c8*8);
    *(uint4*)&KV[s*128 + c8*8] = *(const uint4*)(kk + (size_t)(b*128+s)*512 + (h>>2)*128 + c8*8);
  }
  __syncthreads();
  f32x4 sac[2][8];
  #pragma unroll
  for (int mt = 0; mt < 2; ++mt)
    #pragma unroll
    for (int nt = 0; nt < 8; ++nt) sac[mt][nt] = (f32x4){0.f,0.f,0.f,0.f};
  for (int ks = 0; ks < 128; ks += 32){
    short8 a[2], bb[8];
    #pragma unroll
    for (int mt = 0; mt < 2; ++mt) a[mt] = *(const short8*)&QP[(w*32 + mt*16 + lr)*128 + ks + lg*8];
    #pragma unroll
    for (int nt = 0; nt < 8; ++nt) bb[nt] = *(const short8*)&KV[(nt*16 + lr)*128 + ks + lg*8];
    #pragma unroll
    for (int mt = 0; mt < 2; ++mt)
      #pragma unroll
      for (int nt = 0; nt < 8; ++nt)
        sac[mt][nt] = __builtin_amdgcn_mfma_f32_16x16x32_bf16(a[mt], bb[nt], sac[mt][nt], 0, 0, 0);
  }
  const float NEG = -1e9f, scl = 0.08838834764831845f;
  float mbias[8];
  #pragma unroll
  for (int nt = 0; nt < 8; ++nt) mbias[nt] = (mask[b*128 + nt*16 + lr] > 0) ? 0.f : NEG;
  #pragma unroll
  for (int mt = 0; mt < 2; ++mt)
    #pragma unroll
    for (int rg = 0; rg < 4; ++rg){
      int row = w*32 + mt*16 + lg*4 + rg;
      float vvv[8]; float mx = -3e38f;
      #pragma unroll
      for (int nt = 0; nt < 8; ++nt){
        int col = nt*16 + lr;
        float s_ = sac[mt][nt][rg]*scl + ((col <= row) ? mbias[nt] : NEG);
        vvv[nt] = s_; mx = fmaxf(mx, s_);
      }
      #pragma unroll
      for (int m_ = 1; m_ < 16; m_ <<= 1) mx = fmaxf(mx, __shfl_xor(mx, m_, 64));
      float sum = 0.f;
      #pragma unroll
      for (int nt = 0; nt < 8; ++nt){ vvv[nt] = __expf(vvv[nt]-mx); sum += vvv[nt]; }
      #pragma unroll
      for (int m_ = 1; m_ < 16; m_ <<= 1) sum += __shfl_xor(sum, m_, 64);
      float inv = 1.0f/sum;
      #pragma unroll
      for (int nt = 0; nt < 8; ++nt) QP[row*128 + nt*16 + lr] = f2b(vvv[nt]*inv);
    }
  __syncthreads();
  #pragma unroll
  for (int it = 0; it < 8; ++it){
    int fi = it*256 + t; int s = fi >> 4, c8 = fi & 15;
    u16 tmp[8];
    *(uint4*)tmp = *(const uint4*)(vv + (size_t)(b*128+s)*512 + (h>>2)*128 + c8*8);
    #pragma unroll
    for (int j = 0; j < 8; ++j) KV[(c8*8+j)*128 + s] = tmp[j];
  }
  __syncthreads();
  f32x4 oac[2][8];
  #pragma unroll
  for (int mt = 0; mt < 2; ++mt)
    #pragma unroll
    for (int nt = 0; nt < 8; ++nt) oac[mt][nt] = (f32x4){0.f,0.f,0.f,0.f};
  for (int ks = 0; ks < 128; ks += 32){
    short8 a[2], bb[8];
    #pragma unroll
    for (int mt = 0; mt < 2; ++mt) a[mt] = *(const short8*)&QP[(w*32 + mt*16 + lr)*128 + ks + lg*8];
    #pragma unroll
    for (int nt = 0; nt < 8; ++nt) bb[nt] = *(const short8*)&KV[(nt*16 + lr)*128 + ks + lg*8];
    #pragma unroll
    for (int mt = 0; mt < 2; ++mt)
      #pragma unroll
      for (int nt = 0; nt < 8; ++nt)
        oac[mt][nt] = __builtin_amdgcn_mfma_f32_16x16x32_bf16(a[mt], bb[nt], oac[mt][nt], 0, 0, 0);
  }
  #pragma unroll
  for (int mt = 0; mt < 2; ++mt)
    #pragma unroll
    for (int nt = 0; nt < 8; ++nt)
      #pragma unroll
      for (int rg = 0; rg < 4; ++rg){
        int row = w*32 + mt*16 + lg*4 + rg;
        int col = nt*16 + lr;
        ctx[(size_t)(b*128+row)*2048 + h*128 + col] = f2b(oac[mt][nt][rg]);
      }
}

// ---------------- silu(g)*u -> g
__global__ void k_silu(u16* __restrict__ g, const u16* __restrict__ u, int n8){
  int i = blockIdx.x*256 + threadIdx.x;
  if (i >= n8) return;
  u16 gv[8], uv[8];
  *(uint4*)gv = *(const uint4*)(g + (size_t)i*8);
  *(uint4*)uv = *(const uint4*)(u + (size_t)i*8);
  #pragma unroll
  for (int j = 0; j < 8; ++j){
    float x = b2f(gv[j]), y = b2f(uv[j]);
    float s = x / (1.0f + __expf(-x));
    gv[j] = f2b(s*y);
  }
  *(uint4*)(g + (size_t)i*8) = *(uint4*)gv;
}

// ---------------- final norm + last-token gather
__global__ void k_final(const float* __restrict__ h, const int* __restrict__ mask,
                        const float* __restrict__ w, float* __restrict__ out){
  __shared__ float red[4]; __shared__ int rowsh;
  int b = blockIdx.x, t = threadIdx.x;
  if (t == 0){
    int c = 0;
    for (int i = 0; i < 128; ++i) c += (mask[b*128+i] > 0);
    rowsh = b*128 + c - 1;
  }
  __syncthreads();
  const float* hr = h + (size_t)rowsh*D_;
  float ss = 0.f;
  for (int i = t; i < D_; i += 256){ float x = hr[i]; ss += x*x; }
  #pragma unroll
  for (int m = 32; m; m >>= 1) ss += __shfl_xor(ss, m, 64);
  if ((t & 63) == 0) red[t >> 6] = ss;
  __syncthreads();
  float sc = rsqrtf((red[0]+red[1]+red[2]+red[3]) * (1.0f/D_) + EPS_);
  for (int i = t; i < D_; i += 256) out[(size_t)b*D_ + i] = hr[i]*sc*w[i];
}

extern "C" void kernel_launch(void* const* d_in, const int* in_sizes, int n_in,
                              void* d_out, int out_size, void* d_ws, size_t ws_size,
                              hipStream_t stream) {
  const int*   ids       = (const int*)  d_in[0];
  const int*   mask      = (const int*)  d_in[1];
  const float* embed     = (const float*)d_in[2];
  const float* attn_norm = (const float*)d_in[3];
  const float* mlp_norm  = (const float*)d_in[4];
  const float* fin_norm  = (const float*)d_in[5];
  struct QW { const int* c; const float* am; const float* A; const float* B; };
  auto qw = [&](int i){ return QW{(const int*)d_in[i], (const float*)d_in[i+1],
                                  (const float*)d_in[i+2], (const float*)d_in[i+3]}; };
  QW Wq = qw(6), Wk = qw(10), Wv = qw(14), Wo = qw(18), Wg = qw(22), Wu = qw(26), Wd = qw(30);

  // workspace layout (132 MB total, ws >= 138,412,032 known-good)
  char* ws = (char*)d_ws;
  float* h  = (float*)(ws);                       // 16 MB
  u16* xb   = (u16*)(ws + 16777216);              // 8 MB (x / ctx)
  u16* qb   = (u16*)(ws + 25165824);              // 8 MB
  u16* kb_  = (u16*)(ws + 33554432);              // 2 MB
  u16* vb   = (u16*)(ws + 35651584);              // 2 MB
  u16* gb   = (u16*)(ws + 37748736);              // 32 MB
  u16* ub   = (u16*)(ws + 71303168);              // 32 MB
  u16* Wb   = (u16*)(ws + 104857600);             // 32 MB (folded weights, reused)

  k_embed<<<NTOK_, 256, 0, stream>>>(ids, embed, h);

  for (int l = 0; l < 2; ++l){
    // ---- attention block: fold q,k,v stacked into Wb (3072 x 2048)
    k_rms<<<NTOK_, 256, 0, stream>>>(h, attn_norm + l*D_, xb);
    k_fold<<<dim3(16,16), 256, 0, stream>>>(Wq.c + (size_t)l*D_*D_, Wq.am + (size_t)l*D_*32,
        Wq.A + (size_t)l*R_*D_, Wq.B + (size_t)l*D_*R_, Wb, D_, D_);
    k_fold<<<dim3(16,4), 256, 0, stream>>>(Wk.c + (size_t)l*512*D_, Wk.am + (size_t)l*512*32,
        Wk.A + (size_t)l*R_*D_, Wk.B + (size_t)l*512*R_, Wb + (size_t)2048*D_, 512, D_);
    k_fold<<<dim3(16,4), 256, 0, stream>>>(Wv.c + (size_t)l*512*D_, Wv.am + (size_t)l*512*32,
        Wv.A + (size_t)l*R_*D_, Wv.B + (size_t)l*512*R_, Wb + (size_t)2560*D_, 512, D_);
    k_gemm<2><<<dim3(24,16), 256, 0, stream>>>(xb, Wb, nullptr, qb, kb_, vb, NTOK_, 3072, D_);
    k_rope<<<8192, 256, 0, stream>>>(qb, H_);
    k_rope<<<2048, 256, 0, stream>>>(kb_, HK_);
    k_attn<<<dim3(16,16), 256, 0, stream>>>(qb, kb_, vb, mask, xb);  // ctx -> xb
    k_fold<<<dim3(16,16), 256, 0, stream>>>(Wo.c + (size_t)l*D_*D_, Wo.am + (size_t)l*D_*32,
        Wo.A + (size_t)l*R_*D_, Wo.B + (size_t)l*D_*R_, Wb, D_, D_);
    k_gemm<1><<<dim3(16,16), 256, 0, stream>>>(xb, Wb, h, nullptr, nullptr, nullptr, NTOK_, D_, D_);
    // ---- MLP block
    k_rms<<<NTOK_, 256, 0, stream>>>(h, mlp_norm + l*D_, xb);
    k_fold<<<dim3(16,64), 256, 0, stream>>>(Wg.c + (size_t)l*F_*D_, Wg.am + (size_t)l*F_*32,
        Wg.A + (size_t)l*R_*D_, Wg.B + (size_t)l*F_*R_, Wb, F_, D_);
    k_gemm<0><<<dim3(64,16), 256, 0, stream>>>(xb, Wb, nullptr, gb, nullptr, nullptr, NTOK_, F_, D_);
    k_fold<<<dim3(16,64), 256, 0, stream>>>(Wu.c + (size_t)l*F_*D_, Wu.am + (size_t)l*F_*32,
        Wu.A + (size_t)l*R_*D_, Wu.B + (size_t)l*F_*R_, Wb, F_, D_);
    k_gemm<0><<<dim3(64,16), 256, 0, stream>>>(xb, Wb, nullptr, ub, nullptr, nullptr, NTOK_, F_, D_);
    k_silu<<<8192, 256, 0, stream>>>(gb, ub, NTOK_*F_/8);
    k_fold<<<dim3(64,16), 256, 0, stream>>>(Wd.c + (size_t)l*D_*F_, Wd.am + (size_t)l*D_*128,
        Wd.A + (size_t)l*R_*F_, Wd.B + (size_t)l*D_*R_, Wb, D_, F_);
    k_gemm<1><<<dim3(16,16), 256, 0, stream>>>(gb, Wb, h, nullptr, nullptr, nullptr, NTOK_, D_, F_);
  }
  k_final<<<16, 256, 0, stream>>>(h, mask, fin_norm, (float*)d_out);
}

// Round 3
// 1689.194 us; speedup vs baseline: 1.2629x; 1.1964x over previous
//
#include <hip/hip_runtime.h>
#include <stdint.h>

#define D_ 2048
#define H_ 16
#define HK_ 4
#define F_ 8192
#define R_ 64
#define NTOK_ 2048
#define EPS_ 1e-5f

typedef unsigned short u16;
typedef short short8 __attribute__((ext_vector_type(8)));
typedef float f32x4 __attribute__((ext_vector_type(4)));

__constant__ float NF4_TAB[16] = {
  -1.0f, -0.6961928009986877f, -0.5250730514526367f, -0.39491748809814453f,
  -0.28444138169288635f, -0.18477343022823334f, -0.09105003625154495f, 0.0f,
  0.07958029955625534f, 0.16093020141124725f, 0.24611230194568634f, 0.33791524171829224f,
  0.44070982933044434f, 0.5626170039176941f, 0.7229568362236023f, 1.0f };

static __device__ __forceinline__ float b2f(u16 u){ return __uint_as_float(((unsigned)u)<<16); }
static __device__ __forceinline__ u16 f2b(float f){
  unsigned u = __float_as_uint(f);
  return (u16)((u + 0x7fffu + ((u>>16)&1u)) >> 16);
}

// ---------------- embedding gather
__global__ void k_embed(const int* __restrict__ ids, const float* __restrict__ embed,
                        float* __restrict__ h){
  int tok = blockIdx.x;
  int id  = ids[tok];
  const float4* src = (const float4*)(embed + (size_t)id * D_);
  float4* dst = (float4*)(h + (size_t)tok * D_);
  for (int i = threadIdx.x; i < D_/4; i += 256) dst[i] = src[i];
}

// ---------------- RMSNorm
__global__ void k_rms(const float* __restrict__ h, const float* __restrict__ w,
                      u16* __restrict__ xb){
  __shared__ float red[4];
  int row = blockIdx.x, t = threadIdx.x;
  const float* hr = h + (size_t)row * D_;
  float ss = 0.f;
  for (int i = t; i < D_; i += 256){ float v = hr[i]; ss += v*v; }
  #pragma unroll
  for (int m = 32; m; m >>= 1) ss += __shfl_xor(ss, m, 64);
  if ((t & 63) == 0) red[t >> 6] = ss;
  __syncthreads();
  float sc = rsqrtf((red[0]+red[1]+red[2]+red[3]) * (1.0f/D_) + EPS_);
  for (int i = t; i < D_; i += 256) xb[(size_t)row*D_ + i] = f2b(hr[i]*sc*w[i]);
}

// ---------------- fold-dequant: W[n,k] = NF4[codes]*absmax + 2 * B@A
__global__ __launch_bounds__(256) void k_fold(const int* __restrict__ codes,
      const float* __restrict__ absmax, const float* __restrict__ Amat,
      const float* __restrict__ Bmat, u16* __restrict__ W, int O, int I){
  __shared__ u16  A_l[64*128];
  __shared__ float Bt_l[64*132];
  __shared__ float nf4s[16];
  int t = threadIdx.x;
  int n0 = blockIdx.y*128, k0 = blockIdx.x*128;
  if (t < 16) nf4s[t] = NF4_TAB[t];
  #pragma unroll
  for (int it = 0; it < 8; ++it){
    int fi = it*256 + t;
    int r = fi >> 5, c4 = fi & 31;
    float4 v = *(const float4*)(Amat + (size_t)r*I + k0 + c4*4);
    uint2 p; p.x = (unsigned)f2b(v.x) | ((unsigned)f2b(v.y)<<16);
    p.y = (unsigned)f2b(v.z) | ((unsigned)f2b(v.w)<<16);
    *(uint2*)&A_l[r*128 + c4*4] = p;
  }
  #pragma unroll
  for (int it = 0; it < 8; ++it){
    int fi = it*256 + t; int nl = fi >> 4, r4 = fi & 15;
    float4 v = *(const float4*)(Bmat + (size_t)(n0+nl)*R_ + r4*4);
    Bt_l[(r4*4+0)*132 + nl] = v.x; Bt_l[(r4*4+1)*132 + nl] = v.y;
    Bt_l[(r4*4+2)*132 + nl] = v.z; Bt_l[(r4*4+3)*132 + nl] = v.w;
  }
  __syncthreads();
  int tk = t & 15, tn = t >> 4;
  float acc[8][8];
  #pragma unroll
  for (int j = 0; j < 8; ++j)
    #pragma unroll
    for (int q = 0; q < 8; ++q) acc[j][q] = 0.f;
  for (int r = 0; r < 64; ++r){
    short8 a8 = *(const short8*)&A_l[r*128 + tk*8];
    float av[8];
    #pragma unroll
    for (int q = 0; q < 8; ++q) av[q] = b2f((u16)a8[q]);
    float4 b0 = *(const float4*)&Bt_l[r*132 + tn*8];
    float4 b1 = *(const float4*)&Bt_l[r*132 + tn*8 + 4];
    float bv[8] = {b0.x,b0.y,b0.z,b0.w,b1.x,b1.y,b1.z,b1.w};
    #pragma unroll
    for (int j = 0; j < 8; ++j)
      #pragma unroll
      for (int q = 0; q < 8; ++q) acc[j][q] += bv[j]*av[q];
  }
  int kb = k0 + tk*8;
  #pragma unroll
  for (int j = 0; j < 8; ++j){
    int n = n0 + tn*8 + j;
    float am = absmax[(size_t)n*(I>>6) + (kb>>6)];
    int4 c0 = *(const int4*)(codes + (size_t)n*I + kb);
    int4 c1 = *(const int4*)(codes + (size_t)n*I + kb + 4);
    u16 o[8];
    o[0]=f2b(nf4s[c0.x&15]*am + 2.0f*acc[j][0]);
    o[1]=f2b(nf4s[c0.y&15]*am + 2.0f*acc[j][1]);
    o[2]=f2b(nf4s[c0.z&15]*am + 2.0f*acc[j][2]);
    o[3]=f2b(nf4s[c0.w&15]*am + 2.0f*acc[j][3]);
    o[4]=f2b(nf4s[c1.x&15]*am + 2.0f*acc[j][4]);
    o[5]=f2b(nf4s[c1.y&15]*am + 2.0f*acc[j][5]);
    o[6]=f2b(nf4s[c1.z&15]*am + 2.0f*acc[j][6]);
    o[7]=f2b(nf4s[c1.w&15]*am + 2.0f*acc[j][7]);
    uint4 pk;
    pk.x=(unsigned)o[0]|((unsigned)o[1]<<16); pk.y=(unsigned)o[2]|((unsigned)o[3]<<16);
    pk.z=(unsigned)o[4]|((unsigned)o[5]<<16); pk.w=(unsigned)o[6]|((unsigned)o[7]<<16);
    *(uint4*)(W + (size_t)n*I + kb) = pk;
  }
}

// ---------------- main GEMM: VGPR-staged double-buffer, depth-2 prefetch,
// one raw s_barrier per iter with lgkmcnt-only wait (no vmcnt drain).
// C[m,n] = sum_k A[m,k]*B[n,k], both bf16 row-major ld=K.
// EPI 0: C0=bf16  EPI 1: Cf+=acc  EPI 2: split-N qkv epilogue
template<int EPI>
__global__ __launch_bounds__(256,3) void k_gemm(const u16* __restrict__ A,
      const u16* __restrict__ B, float* __restrict__ Cf, u16* __restrict__ C0,
      u16* __restrict__ C1, u16* __restrict__ C2, int M, int N, int K){
  __shared__ u16 SA[2][128*32];
  __shared__ u16 SB[2][128*32];
  int t = threadIdx.x;
  int n0 = blockIdx.x*128, m0 = blockIdx.y*128;
  int w = t >> 6, lane = t & 63;
  int mw = (w >> 1)*64, nw = (w & 1)*64;
  int lr = lane & 15, lg = lane >> 4;
  f32x4 acc[4][4];
  #pragma unroll
  for (int mt = 0; mt < 4; ++mt)
    #pragma unroll
    for (int nt = 0; nt < 4; ++nt) acc[mt][nt] = (f32x4){0.f,0.f,0.f,0.f};
  const u16* Ag = A + (size_t)(m0 + (t>>2))*K + (t&3)*8;
  const u16* Bg = B + (size_t)(n0 + (t>>2))*K + (t&3)*8;
  int t8 = t*8;
  int niter = K >> 5;   // always even (>=64)

  uint4 ra0, ra1, rb0, rb1;   // stage set for even iters
  uint4 sa0, sa1, sb0, sb1;   // stage set for odd iters
  auto gload = [&](int it, uint4& a0, uint4& a1, uint4& b0, uint4& b1){
    int kb = it*32;
    a0 = *(const uint4*)(Ag + kb);
    a1 = *(const uint4*)(Ag + (size_t)64*K + kb);
    b0 = *(const uint4*)(Bg + kb);
    b1 = *(const uint4*)(Bg + (size_t)64*K + kb);
  };
  gload(0, ra0, ra1, rb0, rb1);
  gload(1, sa0, sa1, sb0, sb1);

  auto step = [&](int buf, uint4& a0, uint4& a1, uint4& b0, uint4& b1, int pf){
    // ds_write: compiler emits precise vmcnt wait for THESE regs only
    *(uint4*)&SA[buf][t8]        = a0;
    *(uint4*)&SA[buf][2048 + t8] = a1;
    *(uint4*)&SB[buf][t8]        = b0;
    *(uint4*)&SB[buf][2048 + t8] = b1;
    __builtin_amdgcn_s_waitcnt(0xC07F);   // lgkmcnt(0) only; vmcnt untouched
    __builtin_amdgcn_s_barrier();
    // prefetch 2 iters ahead into the regs just written out
    gload(pf, a0, a1, b0, b1);
    short8 af[4], bf_[4];
    #pragma unroll
    for (int mt = 0; mt < 4; ++mt) af[mt]  = *(const short8*)&SA[buf][(mw + mt*16 + lr)*32 + lg*8];
    #pragma unroll
    for (int nt = 0; nt < 4; ++nt) bf_[nt] = *(const short8*)&SB[buf][(nw + nt*16 + lr)*32 + lg*8];
    #pragma unroll
    for (int mt = 0; mt < 4; ++mt)
      #pragma unroll
      for (int nt = 0; nt < 4; ++nt)
        acc[mt][nt] = __builtin_amdgcn_mfma_f32_16x16x32_bf16(af[mt], bf_[nt], acc[mt][nt], 0, 0, 0);
  };

  for (int k = 0; k < niter; k += 2){
    step(0, ra0, ra1, rb0, rb1, (k+2 < niter) ? k+2 : k);
    step(1, sa0, sa1, sb0, sb1, (k+3 < niter) ? k+3 : k+1);
  }

  // epilogue
  u16* cb_ = C0; int ldc = N; int coff = n0;
  if (EPI == 2){
    if (n0 < 2048)      { cb_ = C0; ldc = 2048; coff = n0; }
    else if (n0 < 2560) { cb_ = C1; ldc = 512;  coff = n0 - 2048; }
    else                { cb_ = C2; ldc = 512;  coff = n0 - 2560; }
  }
  #pragma unroll
  for (int mt = 0; mt < 4; ++mt)
    #pragma unroll
    for (int nt = 0; nt < 4; ++nt){
      int cl = nw + nt*16 + lr;
      #pragma unroll
      for (int rg = 0; rg < 4; ++rg){
        int row = m0 + mw + mt*16 + lg*4 + rg;
        float v = acc[mt][nt][rg];
        if (EPI == 1) Cf[(size_t)row*N + n0 + cl] += v;
        else          cb_[(size_t)row*ldc + coff + cl] = f2b(v);
      }
    }
}

// ---------------- RoPE in-place on bf16 [tok][nh*128]
__global__ void k_rope(u16* __restrict__ x, int nh){
  int i = blockIdx.x*256 + threadIdx.x;
  int d = i & 63; int rem = i >> 6; int hh = rem % nh; int tok = rem / nh;
  int s = tok & 127;
  size_t base = (size_t)tok*nh*128 + hh*128 + d;
  float x1 = b2f(x[base]), x2 = b2f(x[base+64]);
  float inv = exp2f(-(float)d * 0.20762050581352868f);
  float ang = (float)s * inv;
  float sn = sinf(ang), cs = cosf(ang);
  x[base]      = f2b(x1*cs - x2*sn);
  x[base+64]   = f2b(x2*cs + x1*sn);
}

// ---------------- attention: one block per (b, head); S=128, HD=128
__global__ __launch_bounds__(256) void k_attn(const u16* __restrict__ q,
      const u16* __restrict__ kk, const u16* __restrict__ vv,
      const int* __restrict__ mask, u16* __restrict__ ctx){
  __shared__ u16 QP[128*128];
  __shared__ u16 KV[128*128];
  int b = blockIdx.y, h = blockIdx.x;
  int t = threadIdx.x, w = t >> 6, lane = t & 63;
  int lr = lane & 15, lg = lane >> 4;
  #pragma unroll
  for (int it = 0; it < 8; ++it){
    int fi = it*256 + t; int s = fi >> 4, c8 = fi & 15;
    *(uint4*)&QP[s*128 + c8*8] = *(const uint4*)(q  + (size_t)(b*128+s)*2048 + h*128 + c8*8);
    *(uint4*)&KV[s*128 + c8*8] = *(const uint4*)(kk + (size_t)(b*128+s)*512 + (h>>2)*128 + c8*8);
  }
  __syncthreads();
  f32x4 sac[2][8];
  #pragma unroll
  for (int mt = 0; mt < 2; ++mt)
    #pragma unroll
    for (int nt = 0; nt < 8; ++nt) sac[mt][nt] = (f32x4){0.f,0.f,0.f,0.f};
  for (int ks = 0; ks < 128; ks += 32){
    short8 a[2], bb[8];
    #pragma unroll
    for (int mt = 0; mt < 2; ++mt) a[mt] = *(const short8*)&QP[(w*32 + mt*16 + lr)*128 + ks + lg*8];
    #pragma unroll
    for (int nt = 0; nt < 8; ++nt) bb[nt] = *(const short8*)&KV[(nt*16 + lr)*128 + ks + lg*8];
    #pragma unroll
    for (int mt = 0; mt < 2; ++mt)
      #pragma unroll
      for (int nt = 0; nt < 8; ++nt)
        sac[mt][nt] = __builtin_amdgcn_mfma_f32_16x16x32_bf16(a[mt], bb[nt], sac[mt][nt], 0, 0, 0);
  }
  const float NEG = -1e9f, scl = 0.08838834764831845f;
  float mbias[8];
  #pragma unroll
  for (int nt = 0; nt < 8; ++nt) mbias[nt] = (mask[b*128 + nt*16 + lr] > 0) ? 0.f : NEG;
  #pragma unroll
  for (int mt = 0; mt < 2; ++mt)
    #pragma unroll
    for (int rg = 0; rg < 4; ++rg){
      int row = w*32 + mt*16 + lg*4 + rg;
      float vvv[8]; float mx = -3e38f;
      #pragma unroll
      for (int nt = 0; nt < 8; ++nt){
        int col = nt*16 + lr;
        float s_ = sac[mt][nt][rg]*scl + ((col <= row) ? mbias[nt] : NEG);
        vvv[nt] = s_; mx = fmaxf(mx, s_);
      }
      #pragma unroll
      for (int m_ = 1; m_ < 16; m_ <<= 1) mx = fmaxf(mx, __shfl_xor(mx, m_, 64));
      float sum = 0.f;
      #pragma unroll
      for (int nt = 0; nt < 8; ++nt){ vvv[nt] = __expf(vvv[nt]-mx); sum += vvv[nt]; }
      #pragma unroll
      for (int m_ = 1; m_ < 16; m_ <<= 1) sum += __shfl_xor(sum, m_, 64);
      float inv = 1.0f/sum;
      #pragma unroll
      for (int nt = 0; nt < 8; ++nt) QP[row*128 + nt*16 + lr] = f2b(vvv[nt]*inv);
    }
  __syncthreads();
  #pragma unroll
  for (int it = 0; it < 8; ++it){
    int fi = it*256 + t; int s = fi >> 4, c8 = fi & 15;
    u16 tmp[8];
    *(uint4*)tmp = *(const uint4*)(vv + (size_t)(b*128+s)*512 + (h>>2)*128 + c8*8);
    #pragma unroll
    for (int j = 0; j < 8; ++j) KV[(c8*8+j)*128 + s] = tmp[j];
  }
  __syncthreads();
  f32x4 oac[2][8];
  #pragma unroll
  for (int mt = 0; mt < 2; ++mt)
    #pragma unroll
    for (int nt = 0; nt < 8; ++nt) oac[mt][nt] = (f32x4){0.f,0.f,0.f,0.f};
  for (int ks = 0; ks < 128; ks += 32){
    short8 a[2], bb[8];
    #pragma unroll
    for (int mt = 0; mt < 2; ++mt) a[mt] = *(const short8*)&QP[(w*32 + mt*16 + lr)*128 + ks + lg*8];
    #pragma unroll
    for (int nt = 0; nt < 8; ++nt) bb[nt] = *(const short8*)&KV[(nt*16 + lr)*128 + ks + lg*8];
    #pragma unroll
    for (int mt = 0; mt < 2; ++mt)
      #pragma unroll
      for (int nt = 0; nt < 8; ++nt)
        oac[mt][nt] = __builtin_amdgcn_mfma_f32_16x16x32_bf16(a[mt], bb[nt], oac[mt][nt], 0, 0, 0);
  }
  #pragma unroll
  for (int mt = 0; mt < 2; ++mt)
    #pragma unroll
    for (int nt = 0; nt < 8; ++nt)
      #pragma unroll
      for (int rg = 0; rg < 4; ++rg){
        int row = w*32 + mt*16 + lg*4 + rg;
        int col = nt*16 + lr;
        ctx[(size_t)(b*128+row)*2048 + h*128 + col] = f2b(oac[mt][nt][rg]);
      }
}

// ---------------- silu(g)*u -> g
__global__ void k_silu(u16* __restrict__ g, const u16* __restrict__ u, int n8){
  int i = blockIdx.x*256 + threadIdx.x;
  if (i >= n8) return;
  u16 gv[8], uv[8];
  *(uint4*)gv = *(const uint4*)(g + (size_t)i*8);
  *(uint4*)uv = *(const uint4*)(u + (size_t)i*8);
  #pragma unroll
  for (int j = 0; j < 8; ++j){
    float x = b2f(gv[j]), y = b2f(uv[j]);
    float s = x / (1.0f + __expf(-x));
    gv[j] = f2b(s*y);
  }
  *(uint4*)(g + (size_t)i*8) = *(uint4*)gv;
}

// ---------------- final norm + last-token gather
__global__ void k_final(const float* __restrict__ h, const int* __restrict__ mask,
                        const float* __restrict__ w, float* __restrict__ out){
  __shared__ float red[4]; __shared__ int rowsh;
  int b = blockIdx.x, t = threadIdx.x;
  if (t == 0){
    int c = 0;
    for (int i = 0; i < 128; ++i) c += (mask[b*128+i] > 0);
    rowsh = b*128 + c - 1;
  }
  __syncthreads();
  const float* hr = h + (size_t)rowsh*D_;
  float ss = 0.f;
  for (int i = t; i < D_; i += 256){ float x = hr[i]; ss += x*x; }
  #pragma unroll
  for (int m = 32; m; m >>= 1) ss += __shfl_xor(ss, m, 64);
  if ((t & 63) == 0) red[t >> 6] = ss;
  __syncthreads();
  float sc = rsqrtf((red[0]+red[1]+red[2]+red[3]) * (1.0f/D_) + EPS_);
  for (int i = t; i < D_; i += 256) out[(size_t)b*D_ + i] = hr[i]*sc*w[i];
}

extern "C" void kernel_launch(void* const* d_in, const int* in_sizes, int n_in,
                              void* d_out, int out_size, void* d_ws, size_t ws_size,
                              hipStream_t stream) {
  const int*   ids       = (const int*)  d_in[0];
  const int*   mask      = (const int*)  d_in[1];
  const float* embed     = (const float*)d_in[2];
  const float* attn_norm = (const float*)d_in[3];
  const float* mlp_norm  = (const float*)d_in[4];
  const float* fin_norm  = (const float*)d_in[5];
  struct QW { const int* c; const float* am; const float* A; const float* B; };
  auto qw = [&](int i){ return QW{(const int*)d_in[i], (const float*)d_in[i+1],
                                  (const float*)d_in[i+2], (const float*)d_in[i+3]}; };
  QW Wq = qw(6), Wk = qw(10), Wv = qw(14), Wo = qw(18), Wg = qw(22), Wu = qw(26), Wd = qw(30);

  // workspace layout
  char* ws = (char*)d_ws;
  float* h  = (float*)(ws);                       // 16 MB
  u16* xb   = (u16*)(ws + 16777216);              // 8 MB (x / ctx)
  u16* qb   = (u16*)(ws + 25165824);              // 8 MB
  u16* kb_  = (u16*)(ws + 33554432);              // 2 MB
  u16* vb   = (u16*)(ws + 35651584);              // 2 MB
  u16* gb   = (u16*)(ws + 37748736);              // 32 MB
  u16* ub   = (u16*)(ws + 71303168);              // 32 MB
  u16* Wb   = (u16*)(ws + 104857600);             // 32 MB (folded weights, reused)

  k_embed<<<NTOK_, 256, 0, stream>>>(ids, embed, h);

  for (int l = 0; l < 2; ++l){
    // ---- attention block: fold q,k,v stacked into Wb (3072 x 2048)
    k_rms<<<NTOK_, 256, 0, stream>>>(h, attn_norm + l*D_, xb);
    k_fold<<<dim3(16,16), 256, 0, stream>>>(Wq.c + (size_t)l*D_*D_, Wq.am + (size_t)l*D_*32,
        Wq.A + (size_t)l*R_*D_, Wq.B + (size_t)l*D_*R_, Wb, D_, D_);
    k_fold<<<dim3(16,4), 256, 0, stream>>>(Wk.c + (size_t)l*512*D_, Wk.am + (size_t)l*512*32,
        Wk.A + (size_t)l*R_*D_, Wk.B + (size_t)l*512*R_, Wb + (size_t)2048*D_, 512, D_);
    k_fold<<<dim3(16,4), 256, 0, stream>>>(Wv.c + (size_t)l*512*D_, Wv.am + (size_t)l*512*32,
        Wv.A + (size_t)l*R_*D_, Wv.B + (size_t)l*512*R_, Wb + (size_t)2560*D_, 512, D_);
    k_gemm<2><<<dim3(24,16), 256, 0, stream>>>(xb, Wb, nullptr, qb, kb_, vb, NTOK_, 3072, D_);
    k_rope<<<8192, 256, 0, stream>>>(qb, H_);
    k_rope<<<2048, 256, 0, stream>>>(kb_, HK_);
    k_attn<<<dim3(16,16), 256, 0, stream>>>(qb, kb_, vb, mask, xb);  // ctx -> xb
    k_fold<<<dim3(16,16), 256, 0, stream>>>(Wo.c + (size_t)l*D_*D_, Wo.am + (size_t)l*D_*32,
        Wo.A + (size_t)l*R_*D_, Wo.B + (size_t)l*D_*R_, Wb, D_, D_);
    k_gemm<1><<<dim3(16,16), 256, 0, stream>>>(xb, Wb, h, nullptr, nullptr, nullptr, NTOK_, D_, D_);
    // ---- MLP block
    k_rms<<<NTOK_, 256, 0, stream>>>(h, mlp_norm + l*D_, xb);
    k_fold<<<dim3(16,64), 256, 0, stream>>>(Wg.c + (size_t)l*F_*D_, Wg.am + (size_t)l*F_*32,
        Wg.A + (size_t)l*R_*D_, Wg.B + (size_t)l*F_*R_, Wb, F_, D_);
    k_gemm<0><<<dim3(64,16), 256, 0, stream>>>(xb, Wb, nullptr, gb, nullptr, nullptr, NTOK_, F_, D_);
    k_fold<<<dim3(16,64), 256, 0, stream>>>(Wu.c + (size_t)l*F_*D_, Wu.am + (size_t)l*F_*32,
        Wu.A + (size_t)l*R_*D_, Wu.B + (size_t)l*F_*R_, Wb, F_, D_);
    k_gemm<0><<<dim3(64,16), 256, 0, stream>>>(xb, Wb, nullptr, ub, nullptr, nullptr, NTOK_, F_, D_);
    k_silu<<<8192, 256, 0, stream>>>(gb, ub, NTOK_*F_/8);
    k_fold<<<dim3(64,16), 256, 0, stream>>>(Wd.c + (size_t)l*D_*F_, Wd.am + (size_t)l*D_*128,
        Wd.A + (size_t)l*R_*F_, Wd.B + (size_t)l*D_*R_, Wb, D_, F_);
    k_gemm<1><<<dim3(16,16), 256, 0, stream>>>(gb, Wb, h, nullptr, nullptr, nullptr, NTOK_, D_, F_);
  }
  k_final<<<16, 256, 0, stream>>>(h, mask, fin_norm, (float*)d_out);
}